// Round 4
// baseline (77.399 us; speedup 1.0000x reference)
//
#include <hip/hip_runtime.h>
#include <math.h>

// Problem constants
#define NCH   128      // DIM
#define HH    128
#define WW    128
#define NB    8        // batch
#define KS    7
#define MSIZE (128*7*128)        // [u][b][c]
#define CSIZE (128*128*128)      // [u][v][c]

typedef float f32x4 __attribute__((ext_vector_type(4)));

// Separable DFT intermediates: M[u,b,c] = sum_a K[a,b,c] * exp(-2pi i * u*(a-3)/128)
__device__ float g_MAr[MSIZE];
__device__ float g_MAi[MSIZE];
__device__ float g_MBr[MSIZE];
__device__ float g_MBi[MSIZE];
// Final coefficient field C[u][v][c] = S(A_f) * B_f  (complex)
__device__ float g_Cr[CSIZE];
__device__ float g_Ci[CSIZE];

// Kernel 1: build M arrays (A gets 0.9*tanh(A*decay) applied first).
__global__ void kern_factor(const float* __restrict__ A, const float* __restrict__ B) {
    int idx = blockIdx.x * blockDim.x + threadIdx.x;
    if (idx >= MSIZE) return;
    int c  = idx & 127;
    int ub = idx >> 7;
    int b  = ub % 7;
    int u  = ub / 7;

    const float W0 = -6.283185307179586f / 128.0f;
    float mar = 0.f, mai = 0.f, mbr = 0.f, mbi = 0.f;
    float db = (float)(b - 3);
#pragma unroll
    for (int a = 0; a < 7; ++a) {
        float da   = (float)(a - 3);
        float dist = sqrtf(da * da + db * db);
        float dec  = expf(-0.1f * dist);          // exp(-0.3*dist/center), center=3
        float ka   = 0.9f * tanhf(A[c * 49 + a * 7 + b] * dec);
        float kb   = B[c * 49 + a * 7 + b];
        float th   = W0 * (float)(u * (a - 3));
        float s, cc;
        sincosf(th, &s, &cc);                     // exp(i*th) = cc + i*s
        mar = fmaf(ka, cc, mar);
        mai = fmaf(ka, s,  mai);
        mbr = fmaf(kb, cc, mbr);
        mbi = fmaf(kb, s,  mbi);
    }
    g_MAr[idx] = mar;
    g_MAi[idx] = mai;
    g_MBr[idx] = mbr;
    g_MBi[idx] = mbi;
}

// Kernel 2: finish the DFT (7-term b-sum), form S = (1+A)(1+A^2)(1+A^4)(1+A^8),
// store C = S*Bf into g_Cr/g_Ci. 256 threads: 8 v per block, 32 lanes x float4 ch.
__global__ void kern_coef() {
    __shared__ float s_cs[128];
    __shared__ float s_sn[128];
    int t = threadIdx.x;
    if (t < 128) {
        float th = (6.283185307179586f / 128.0f) * (float)t;
        float s, c;
        sincosf(th, &s, &c);
        s_cs[t] = c;
        s_sn[t] = s;
    }
    __syncthreads();

    int bid = blockIdx.x;              // 0..2047
    int u   = bid >> 4;                // 0..127
    int v   = ((bid & 15) << 3) + (t >> 5);   // 0..127
    int c0  = (t & 31) << 2;           // 0,4,...,124

    float Afr[4] = {0, 0, 0, 0}, Afi[4] = {0, 0, 0, 0};
    float Bfr[4] = {0, 0, 0, 0}, Bfi[4] = {0, 0, 0, 0};

#pragma unroll
    for (int b = 0; b < 7; ++b) {
        int p = (v * (b - 3)) & 127;           // mod 128
        float wr = s_cs[p];
        float wi = -s_sn[p];                   // exp(-2pi i p/128)
        int mbase = (u * 7 + b) * 128 + c0;
        f32x4 mar = *(const f32x4*)(g_MAr + mbase);
        f32x4 mai = *(const f32x4*)(g_MAi + mbase);
        f32x4 mbr = *(const f32x4*)(g_MBr + mbase);
        f32x4 mbi = *(const f32x4*)(g_MBi + mbase);
#pragma unroll
        for (int j = 0; j < 4; ++j) {
            Afr[j] = fmaf(mar[j], wr, fmaf(-mai[j], wi, Afr[j]));
            Afi[j] = fmaf(mar[j], wi, fmaf( mai[j], wr, Afi[j]));
            Bfr[j] = fmaf(mbr[j], wr, fmaf(-mbi[j], wi, Bfr[j]));
            Bfi[j] = fmaf(mbr[j], wi, fmaf( mbi[j], wr, Bfi[j]));
        }
    }

    f32x4 cr, ci;
#pragma unroll
    for (int j = 0; j < 4; ++j) {
        float ar = Afr[j], ai = Afi[j];
        float a2r = ar * ar - ai * ai,     a2i = 2.f * ar * ai;
        float a4r = a2r * a2r - a2i * a2i, a4i = 2.f * a2r * a2i;
        float a8r = a4r * a4r - a4i * a4i, a8i = 2.f * a4r * a4i;
        float s1r = 1.f + ar,  s1i = ai;
        float s2r = 1.f + a2r, s2i = a2i;
        float pr  = s1r * s2r - s1i * s2i;
        float pi  = s1r * s2i + s1i * s2r;
        float s3r = 1.f + a4r, s3i = a4i;
        float qr  = pr * s3r - pi * s3i;
        float qi  = pr * s3i + pi * s3r;
        float s4r = 1.f + a8r, s4i = a8i;
        float Sr  = qr * s4r - qi * s4i;
        float Si  = qr * s4i + qi * s4r;
        cr[j] = Sr * Bfr[j] - Si * Bfi[j];
        ci[j] = Sr * Bfi[j] + Si * Bfr[j];
    }

    int cbase = ((u << 7) | v) * 128 + c0;
    *(f32x4*)(g_Cr + cbase) = cr;
    *(f32x4*)(g_Ci + cbase) = ci;
}

// Kernel 3: pure streaming elementwise complex multiply, ONE batch-octet-tile
// per block (no in-thread batch loop -> stalls hidden by TLP, not ILP).
// bid = uv*8 + bt : XCD k owns batch-slab k (bid%8==bt), all XCDs share the
// sequentially swept C field in L3.
__global__ void kern_stream(const float* __restrict__ x, float* __restrict__ out) {
    int t   = threadIdx.x;
    int bid = blockIdx.x;              // 0..16383
    int bt  = bid & 7;                 // batch
    int uv  = bid >> 3;                // 0..2047
    int u   = uv >> 4;
    int v   = ((uv & 15) << 3) + (t >> 5);
    int c0  = (t & 31) << 2;

    int cbase = ((u << 7) | v) * 128 + c0;
    f32x4 cr = *(const f32x4*)(g_Cr + cbase);
    f32x4 ci = *(const f32x4*)(g_Ci + cbase);

    size_t base = (((size_t)bt * HH + u) * WW + v) * (2 * NCH) + c0;
    f32x4 xr = *(const f32x4*)(x + base);
    f32x4 xi = *(const f32x4*)(x + base + NCH);
    f32x4 orr, oii;
#pragma unroll
    for (int j = 0; j < 4; ++j) {
        orr[j] = cr[j] * xr[j] - ci[j] * xi[j];
        oii[j] = cr[j] * xi[j] + ci[j] * xr[j];
    }
    __builtin_nontemporal_store(orr, (f32x4*)(out + base));
    __builtin_nontemporal_store(oii, (f32x4*)(out + base + NCH));
}

extern "C" void kernel_launch(void* const* d_in, const int* in_sizes, int n_in,
                              void* d_out, int out_size, void* d_ws, size_t ws_size,
                              hipStream_t stream) {
    const float* x = (const float*)d_in[0];   // (8,128,128,256) f32
    const float* A = (const float*)d_in[1];   // (128,7,7) f32
    const float* B = (const float*)d_in[2];   // (128,7,7) f32
    float* out = (float*)d_out;

    kern_factor<<<(MSIZE + 255) / 256, 256, 0, stream>>>(A, B);
    kern_coef<<<2048, 256, 0, stream>>>();
    kern_stream<<<16384, 256, 0, stream>>>(x, out);
}

// Round 5
// 59.741 us; speedup vs baseline: 1.2956x; 1.2956x over previous
//
#include <hip/hip_runtime.h>
#include <math.h>

// Problem constants
#define NCH   128      // DIM
#define HH    128
#define WW    128
#define NB    8        // batch
#define KS    7
#define MSIZE (128*7*128)        // [u][b][c]

typedef float f32x4 __attribute__((ext_vector_type(4)));

// Separable DFT intermediates: M[u,b,c] = sum_a K[a,b,c] * exp(-2pi i * u*(a-3)/128)
__device__ float g_MAr[MSIZE];
__device__ float g_MAi[MSIZE];
__device__ float g_MBr[MSIZE];
__device__ float g_MBi[MSIZE];

// Kernel 1: build M arrays (A gets 0.9*tanh(A*decay) applied first).
__global__ void kern_factor(const float* __restrict__ A, const float* __restrict__ B) {
    int idx = blockIdx.x * blockDim.x + threadIdx.x;
    if (idx >= MSIZE) return;
    int c  = idx & 127;
    int ub = idx >> 7;
    int b  = ub % 7;
    int u  = ub / 7;

    const float W0 = -6.283185307179586f / 128.0f;
    float mar = 0.f, mai = 0.f, mbr = 0.f, mbi = 0.f;
    float db = (float)(b - 3);
#pragma unroll
    for (int a = 0; a < 7; ++a) {
        float da   = (float)(a - 3);
        float dist = sqrtf(da * da + db * db);
        float dec  = expf(-0.1f * dist);          // exp(-0.3*dist/center), center=3
        float ka   = 0.9f * tanhf(A[c * 49 + a * 7 + b] * dec);
        float kb   = B[c * 49 + a * 7 + b];
        float th   = W0 * (float)(u * (a - 3));
        float s, cc;
        sincosf(th, &s, &cc);                     // exp(i*th) = cc + i*s
        mar = fmaf(ka, cc, mar);
        mai = fmaf(ka, s,  mai);
        mbr = fmaf(kb, cc, mbr);
        mbi = fmaf(kb, s,  mbi);
    }
    g_MAr[idx] = mar;
    g_MAi[idx] = mai;
    g_MBr[idx] = mbr;
    g_MBi[idx] = mbi;
}

// Kernel 2 (fused): finish DFT -> C in registers, then apply to all 8 batches.
// Stage ALL 16 x-loads before any compute/store: 16 outstanding 16B loads per
// thread hides HBM latency via MLP instead of serial round-trips.
__global__ void kern_main(const float* __restrict__ x, float* __restrict__ out) {
    __shared__ float s_cs[128];
    __shared__ float s_sn[128];
    int t = threadIdx.x;
    if (t < 128) {
        float th = (6.283185307179586f / 128.0f) * (float)t;
        float s, c;
        sincosf(th, &s, &c);
        s_cs[t] = c;
        s_sn[t] = s;
    }
    __syncthreads();

    int bid = blockIdx.x;              // 0..2047
    int u   = bid >> 4;                // 0..127
    int v   = ((bid & 15) << 3) + (t >> 5);   // 0..127
    int c0  = (t & 31) << 2;           // 0,4,...,124

    float Afr[4] = {0, 0, 0, 0}, Afi[4] = {0, 0, 0, 0};
    float Bfr[4] = {0, 0, 0, 0}, Bfi[4] = {0, 0, 0, 0};

#pragma unroll
    for (int b = 0; b < 7; ++b) {
        int p = (v * (b - 3)) & 127;           // mod 128
        float wr = s_cs[p];
        float wi = -s_sn[p];                   // exp(-2pi i p/128)
        int mbase = (u * 7 + b) * 128 + c0;
        f32x4 mar = *(const f32x4*)(g_MAr + mbase);
        f32x4 mai = *(const f32x4*)(g_MAi + mbase);
        f32x4 mbr = *(const f32x4*)(g_MBr + mbase);
        f32x4 mbi = *(const f32x4*)(g_MBi + mbase);
#pragma unroll
        for (int j = 0; j < 4; ++j) {
            Afr[j] = fmaf(mar[j], wr, fmaf(-mai[j], wi, Afr[j]));
            Afi[j] = fmaf(mar[j], wi, fmaf( mai[j], wr, Afi[j]));
            Bfr[j] = fmaf(mbr[j], wr, fmaf(-mbi[j], wi, Bfr[j]));
            Bfi[j] = fmaf(mbr[j], wi, fmaf( mbi[j], wr, Bfi[j]));
        }
    }

    // S = (1+A)(1+A^2)(1+A^4)(1+A^8); C = S*Bf
    f32x4 cr, ci;
#pragma unroll
    for (int j = 0; j < 4; ++j) {
        float ar = Afr[j], ai = Afi[j];
        float a2r = ar * ar - ai * ai,     a2i = 2.f * ar * ai;
        float a4r = a2r * a2r - a2i * a2i, a4i = 2.f * a2r * a2i;
        float a8r = a4r * a4r - a4i * a4i, a8i = 2.f * a4r * a4i;
        float s1r = 1.f + ar,  s1i = ai;
        float s2r = 1.f + a2r, s2i = a2i;
        float pr  = s1r * s2r - s1i * s2i;
        float pi  = s1r * s2i + s1i * s2r;
        float s3r = 1.f + a4r, s3i = a4i;
        float qr  = pr * s3r - pi * s3i;
        float qi  = pr * s3i + pi * s3r;
        float s4r = 1.f + a8r, s4i = a8i;
        float Sr  = qr * s4r - qi * s4i;
        float Si  = qr * s4i + qi * s4r;
        cr[j] = Sr * Bfr[j] - Si * Bfi[j];
        ci[j] = Sr * Bfi[j] + Si * Bfr[j];
    }

    // Apply to all batches with full MLP: issue all 16 loads, then compute+store.
    const size_t BS = (size_t)HH * WW * 2 * NCH;      // batch stride in floats
    size_t base = ((size_t)u * WW + v) * (2 * NCH) + c0;

    f32x4 xr[NB], xi[NB];
#pragma unroll
    for (int bt = 0; bt < NB; ++bt) {
        xr[bt] = *(const f32x4*)(x + base + (size_t)bt * BS);
        xi[bt] = *(const f32x4*)(x + base + (size_t)bt * BS + NCH);
    }
#pragma unroll
    for (int bt = 0; bt < NB; ++bt) {
        f32x4 orr, oii;
#pragma unroll
        for (int j = 0; j < 4; ++j) {
            orr[j] = cr[j] * xr[bt][j] - ci[j] * xi[bt][j];
            oii[j] = cr[j] * xi[bt][j] + ci[j] * xr[bt][j];
        }
        *(f32x4*)(out + base + (size_t)bt * BS)       = orr;
        *(f32x4*)(out + base + (size_t)bt * BS + NCH) = oii;
    }
}

extern "C" void kernel_launch(void* const* d_in, const int* in_sizes, int n_in,
                              void* d_out, int out_size, void* d_ws, size_t ws_size,
                              hipStream_t stream) {
    const float* x = (const float*)d_in[0];   // (8,128,128,256) f32
    const float* A = (const float*)d_in[1];   // (128,7,7) f32
    const float* B = (const float*)d_in[2];   // (128,7,7) f32
    float* out = (float*)d_out;

    kern_factor<<<(MSIZE + 255) / 256, 256, 0, stream>>>(A, B);
    kern_main<<<2048, 256, 0, stream>>>(x, out);
}

// Round 6
// 54.381 us; speedup vs baseline: 1.4233x; 1.0986x over previous
//
#include <hip/hip_runtime.h>
#include <math.h>

// Problem constants
#define NCH   128      // DIM
#define HH    128
#define WW    128
#define NB    8        // batch
#define NBH   4        // batches per grid-half
#define KS    7
#define MSIZE (128*7*128)        // [u][b][c]

typedef float f32x4 __attribute__((ext_vector_type(4)));

// Separable DFT intermediates: M[u,b,c] = sum_a K[a,b,c] * exp(-2pi i * u*(a-3)/128)
__device__ float g_MAr[MSIZE];
__device__ float g_MAi[MSIZE];
__device__ float g_MBr[MSIZE];
__device__ float g_MBi[MSIZE];

// Kernel 1: build M arrays (A gets 0.9*tanh(A*decay) applied first).
__global__ void kern_factor(const float* __restrict__ A, const float* __restrict__ B) {
    int idx = blockIdx.x * blockDim.x + threadIdx.x;
    if (idx >= MSIZE) return;
    int c  = idx & 127;
    int ub = idx >> 7;
    int b  = ub % 7;
    int u  = ub / 7;

    const float W0 = -6.283185307179586f / 128.0f;
    float mar = 0.f, mai = 0.f, mbr = 0.f, mbi = 0.f;
    float db = (float)(b - 3);
#pragma unroll
    for (int a = 0; a < 7; ++a) {
        float da   = (float)(a - 3);
        float dist = sqrtf(da * da + db * db);
        float dec  = expf(-0.1f * dist);          // exp(-0.3*dist/center), center=3
        float ka   = 0.9f * tanhf(A[c * 49 + a * 7 + b] * dec);
        float kb   = B[c * 49 + a * 7 + b];
        float th   = W0 * (float)(u * (a - 3));
        float s, cc;
        sincosf(th, &s, &cc);                     // exp(i*th) = cc + i*s
        mar = fmaf(ka, cc, mar);
        mai = fmaf(ka, s,  mai);
        mbr = fmaf(kb, cc, mbr);
        mbi = fmaf(kb, s,  mbi);
    }
    g_MAr[idx] = mar;
    g_MAi[idx] = mai;
    g_MBr[idx] = mbr;
    g_MBi[idx] = mbi;
}

// Kernel 2 (fused): finish DFT -> C in registers, apply to 4 batches per block.
// Grid = 4096: half = bid>>11 selects batches 0-3 / 4-7. Two rounds of blocks
// per CU -> round-2 prologues overlap round-1 streaming. Staged loads are
// fenced with a compiler barrier so all 8 loads are in flight before stores.
__global__ void kern_main(const float* __restrict__ x, float* __restrict__ out) {
    __shared__ float s_cs[128];
    __shared__ float s_sn[128];
    int t = threadIdx.x;
    if (t < 128) {
        float th = (6.283185307179586f / 128.0f) * (float)t;
        float s, c;
        sincosf(th, &s, &c);
        s_cs[t] = c;
        s_sn[t] = s;
    }
    __syncthreads();

    int bid  = blockIdx.x;             // 0..4095
    int half = bid >> 11;              // 0 or 1
    int uv   = bid & 2047;             // 0..2047
    int u    = uv >> 4;                // 0..127
    int v    = ((uv & 15) << 3) + (t >> 5);   // 0..127
    int c0   = (t & 31) << 2;          // 0,4,...,124

    float Afr[4] = {0, 0, 0, 0}, Afi[4] = {0, 0, 0, 0};
    float Bfr[4] = {0, 0, 0, 0}, Bfi[4] = {0, 0, 0, 0};

#pragma unroll
    for (int b = 0; b < 7; ++b) {
        int p = (v * (b - 3)) & 127;           // mod 128
        float wr = s_cs[p];
        float wi = -s_sn[p];                   // exp(-2pi i p/128)
        int mbase = (u * 7 + b) * 128 + c0;
        f32x4 mar = *(const f32x4*)(g_MAr + mbase);
        f32x4 mai = *(const f32x4*)(g_MAi + mbase);
        f32x4 mbr = *(const f32x4*)(g_MBr + mbase);
        f32x4 mbi = *(const f32x4*)(g_MBi + mbase);
#pragma unroll
        for (int j = 0; j < 4; ++j) {
            Afr[j] = fmaf(mar[j], wr, fmaf(-mai[j], wi, Afr[j]));
            Afi[j] = fmaf(mar[j], wi, fmaf( mai[j], wr, Afi[j]));
            Bfr[j] = fmaf(mbr[j], wr, fmaf(-mbi[j], wi, Bfr[j]));
            Bfi[j] = fmaf(mbr[j], wi, fmaf( mbi[j], wr, Bfi[j]));
        }
    }

    // S = (1+A)(1+A^2)(1+A^4)(1+A^8); C = S*Bf
    f32x4 cr, ci;
#pragma unroll
    for (int j = 0; j < 4; ++j) {
        float ar = Afr[j], ai = Afi[j];
        float a2r = ar * ar - ai * ai,     a2i = 2.f * ar * ai;
        float a4r = a2r * a2r - a2i * a2i, a4i = 2.f * a2r * a2i;
        float a8r = a4r * a4r - a4i * a4i, a8i = 2.f * a4r * a4i;
        float s1r = 1.f + ar,  s1i = ai;
        float s2r = 1.f + a2r, s2i = a2i;
        float pr  = s1r * s2r - s1i * s2i;
        float pi  = s1r * s2i + s1i * s2r;
        float s3r = 1.f + a4r, s3i = a4i;
        float qr  = pr * s3r - pi * s3i;
        float qi  = pr * s3i + pi * s3r;
        float s4r = 1.f + a8r, s4i = a8i;
        float Sr  = qr * s4r - qi * s4i;
        float Si  = qr * s4i + qi * s4r;
        cr[j] = Sr * Bfr[j] - Si * Bfi[j];
        ci[j] = Sr * Bfi[j] + Si * Bfr[j];
    }

    // Stream 4 batches: issue ALL 8 loads (fenced), then compute + NT-store.
    const size_t BS = (size_t)HH * WW * 2 * NCH;      // batch stride in floats
    size_t base = ((size_t)u * WW + v) * (2 * NCH) + c0 + (size_t)(half * NBH) * BS;

    f32x4 xr[NBH], xi[NBH];
#pragma unroll
    for (int bt = 0; bt < NBH; ++bt) {
        xr[bt] = *(const f32x4*)(x + base + (size_t)bt * BS);
        xi[bt] = *(const f32x4*)(x + base + (size_t)bt * BS + NCH);
    }
    asm volatile("" ::: "memory");   // loads may not sink past this point
#pragma unroll
    for (int bt = 0; bt < NBH; ++bt) {
        f32x4 orr, oii;
#pragma unroll
        for (int j = 0; j < 4; ++j) {
            orr[j] = cr[j] * xr[bt][j] - ci[j] * xi[bt][j];
            oii[j] = cr[j] * xi[bt][j] + ci[j] * xr[bt][j];
        }
        __builtin_nontemporal_store(orr, (f32x4*)(out + base + (size_t)bt * BS));
        __builtin_nontemporal_store(oii, (f32x4*)(out + base + (size_t)bt * BS + NCH));
    }
}

extern "C" void kernel_launch(void* const* d_in, const int* in_sizes, int n_in,
                              void* d_out, int out_size, void* d_ws, size_t ws_size,
                              hipStream_t stream) {
    const float* x = (const float*)d_in[0];   // (8,128,128,256) f32
    const float* A = (const float*)d_in[1];   // (128,7,7) f32
    const float* B = (const float*)d_in[2];   // (128,7,7) f32
    float* out = (float*)d_out;

    kern_factor<<<(MSIZE + 255) / 256, 256, 0, stream>>>(A, B);
    kern_main<<<4096, 256, 0, stream>>>(x, out);
}

// Round 7
// 54.322 us; speedup vs baseline: 1.4248x; 1.0011x over previous
//
#include <hip/hip_runtime.h>
#include <math.h>

// Problem constants
#define NCH   128      // DIM
#define HH    128
#define WW    128
#define NB    8        // batch
#define NBH   4        // batches per grid-half
#define KS    7
#define MSIZE (128*7*128)        // [u][b][c]

typedef float f32x4 __attribute__((ext_vector_type(4)));

// Force a loaded value to be materialized in registers HERE (keep-alive pin).
#define PIN(v) asm volatile("" : "+v"(v))

// Separable DFT intermediates: M[u,b,c] = sum_a K[a,b,c] * exp(-2pi i * u*(a-3)/128)
__device__ float g_MAr[MSIZE];
__device__ float g_MAi[MSIZE];
__device__ float g_MBr[MSIZE];
__device__ float g_MBi[MSIZE];

// Kernel 1: build M arrays (A gets 0.9*tanh(A*decay) applied first).
__global__ void kern_factor(const float* __restrict__ A, const float* __restrict__ B) {
    int idx = blockIdx.x * blockDim.x + threadIdx.x;
    if (idx >= MSIZE) return;
    int c  = idx & 127;
    int ub = idx >> 7;
    int b  = ub % 7;
    int u  = ub / 7;

    const float W0 = -6.283185307179586f / 128.0f;
    float mar = 0.f, mai = 0.f, mbr = 0.f, mbi = 0.f;
    float db = (float)(b - 3);
#pragma unroll
    for (int a = 0; a < 7; ++a) {
        float da   = (float)(a - 3);
        float dist = sqrtf(da * da + db * db);
        float dec  = expf(-0.1f * dist);          // exp(-0.3*dist/center), center=3
        float ka   = 0.9f * tanhf(A[c * 49 + a * 7 + b] * dec);
        float kb   = B[c * 49 + a * 7 + b];
        float th   = W0 * (float)(u * (a - 3));
        float s, cc;
        sincosf(th, &s, &cc);                     // exp(i*th) = cc + i*s
        mar = fmaf(ka, cc, mar);
        mai = fmaf(ka, s,  mai);
        mbr = fmaf(kb, cc, mbr);
        mbi = fmaf(kb, s,  mbi);
    }
    g_MAr[idx] = mar;
    g_MAi[idx] = mai;
    g_MBr[idx] = mbr;
    g_MBi[idx] = mbi;
}

// Kernel 2 (fused): finish DFT -> C in registers, apply to 4 batches per block.
// Grid = 4096 (2 rounds/CU). Stream phase: issue ALL 8 global_load_dwordx4,
// PIN each result (forces simultaneous materialization -> 8 loads in flight),
// then compute + NT-store.
__global__ void kern_main(const float* __restrict__ x, float* __restrict__ out) {
    __shared__ float s_cs[128];
    __shared__ float s_sn[128];
    int t = threadIdx.x;
    if (t < 128) {
        float th = (6.283185307179586f / 128.0f) * (float)t;
        float s, c;
        sincosf(th, &s, &c);
        s_cs[t] = c;
        s_sn[t] = s;
    }
    __syncthreads();

    int bid  = blockIdx.x;             // 0..4095
    int half = bid >> 11;              // 0 or 1
    int uv   = bid & 2047;             // 0..2047
    int u    = uv >> 4;                // 0..127
    int v    = ((uv & 15) << 3) + (t >> 5);   // 0..127
    int c0   = (t & 31) << 2;          // 0,4,...,124

    float Afr[4] = {0, 0, 0, 0}, Afi[4] = {0, 0, 0, 0};
    float Bfr[4] = {0, 0, 0, 0}, Bfi[4] = {0, 0, 0, 0};

#pragma unroll
    for (int b = 0; b < 7; ++b) {
        int p = (v * (b - 3)) & 127;           // mod 128
        float wr = s_cs[p];
        float wi = -s_sn[p];                   // exp(-2pi i p/128)
        int mbase = (u * 7 + b) * 128 + c0;
        f32x4 mar = *(const f32x4*)(g_MAr + mbase);
        f32x4 mai = *(const f32x4*)(g_MAi + mbase);
        f32x4 mbr = *(const f32x4*)(g_MBr + mbase);
        f32x4 mbi = *(const f32x4*)(g_MBi + mbase);
#pragma unroll
        for (int j = 0; j < 4; ++j) {
            Afr[j] = fmaf(mar[j], wr, fmaf(-mai[j], wi, Afr[j]));
            Afi[j] = fmaf(mar[j], wi, fmaf( mai[j], wr, Afi[j]));
            Bfr[j] = fmaf(mbr[j], wr, fmaf(-mbi[j], wi, Bfr[j]));
            Bfi[j] = fmaf(mbr[j], wi, fmaf( mbi[j], wr, Bfi[j]));
        }
    }

    // S = (1+A)(1+A^2)(1+A^4)(1+A^8); C = S*Bf
    f32x4 cr, ci;
#pragma unroll
    for (int j = 0; j < 4; ++j) {
        float ar = Afr[j], ai = Afi[j];
        float a2r = ar * ar - ai * ai,     a2i = 2.f * ar * ai;
        float a4r = a2r * a2r - a2i * a2i, a4i = 2.f * a2r * a2i;
        float a8r = a4r * a4r - a4i * a4i, a8i = 2.f * a4r * a4i;
        float s1r = 1.f + ar,  s1i = ai;
        float s2r = 1.f + a2r, s2i = a2i;
        float pr  = s1r * s2r - s1i * s2i;
        float pi  = s1r * s2i + s1i * s2r;
        float s3r = 1.f + a4r, s3i = a4i;
        float qr  = pr * s3r - pi * s3i;
        float qi  = pr * s3i + pi * s3r;
        float s4r = 1.f + a8r, s4i = a8i;
        float Sr  = qr * s4r - qi * s4i;
        float Si  = qr * s4i + qi * s4r;
        cr[j] = Sr * Bfr[j] - Si * Bfi[j];
        ci[j] = Sr * Bfi[j] + Si * Bfr[j];
    }

    // Stream 4 batches: all 8 loads issued + pinned live, then compute/store.
    const size_t BS = (size_t)HH * WW * 2 * NCH;      // batch stride in floats
    size_t base = ((size_t)u * WW + v) * (2 * NCH) + c0 + (size_t)(half * NBH) * BS;

    f32x4 xr[NBH], xi[NBH];
#pragma unroll
    for (int bt = 0; bt < NBH; ++bt) {
        xr[bt] = *(const f32x4*)(x + base + (size_t)bt * BS);
        xi[bt] = *(const f32x4*)(x + base + (size_t)bt * BS + NCH);
    }
#pragma unroll
    for (int bt = 0; bt < NBH; ++bt) {
        PIN(xr[bt]);
        PIN(xi[bt]);
    }
#pragma unroll
    for (int bt = 0; bt < NBH; ++bt) {
        f32x4 orr, oii;
#pragma unroll
        for (int j = 0; j < 4; ++j) {
            orr[j] = cr[j] * xr[bt][j] - ci[j] * xi[bt][j];
            oii[j] = cr[j] * xi[bt][j] + ci[j] * xr[bt][j];
        }
        __builtin_nontemporal_store(orr, (f32x4*)(out + base + (size_t)bt * BS));
        __builtin_nontemporal_store(oii, (f32x4*)(out + base + (size_t)bt * BS + NCH));
    }
}

extern "C" void kernel_launch(void* const* d_in, const int* in_sizes, int n_in,
                              void* d_out, int out_size, void* d_ws, size_t ws_size,
                              hipStream_t stream) {
    const float* x = (const float*)d_in[0];   // (8,128,128,256) f32
    const float* A = (const float*)d_in[1];   // (128,7,7) f32
    const float* B = (const float*)d_in[2];   // (128,7,7) f32
    float* out = (float*)d_out;

    kern_factor<<<(MSIZE + 255) / 256, 256, 0, stream>>>(A, B);
    kern_main<<<4096, 256, 0, stream>>>(x, out);
}